// Round 6
// baseline (128.069 us; speedup 1.0000x reference)
//
#include <hip/hip_runtime.h>
#include <hip/hip_fp16.h>

// BasisFunction2D, round 6.
// Kernel 1 (precompute): per x/z value compute grid index + weight once.
//   zc stores {half2(wz,wz) bits, lds_element_offset} so the main loop does
//   zero weight-conversion work.
// Kernel 2 (main): one block per (o-pair, i) -> 1024 blocks, 512 threads
//   = 1 batch element each. Stage P[:,:,{o0,o1},i,:] as PACKED F16 o-pairs
//   (f16 > bf16 precision here: |P|<=3.1e-3, exponent range unused) in
//   38.1 KB LDS -> 4 blocks/CU = 32 waves/CU. Entire trilinear lerp in
//   __half2 packed math (v_pk_fma_f16): both outputs per instruction,
//   no unpack instrs. ~13 VALU/iter vs round 5's ~24 (kernel was VALU-bound).
//   f32 accumulation, atomicAdd over i into out.

#define NG        16
#define NB        17             // NG+1
#define IN_X      32
#define IN_Z      32
#define OUT_DIM   64
#define BATCH     512
#define CELLS     (NB * NB)      // 289
#define LDS_STR   33             // 32 + 1 pad (element units)
#define XSTR      (NB * LDS_STR) // 561 elements per gx step

__device__ __forceinline__ void grid_coord(float v,
                                           const float* __restrict__ borders,
                                           const float* __restrict__ inv_len,
                                           int& idx, float& w) {
    float e   = expf(-fabsf(v));
    float cdf = (v > 0.f) ? (1.f - 0.5f * e) : (0.5f * e);
    int t = (int)(cdf * 16.f);
    t = t < 0 ? 0 : (t > NG - 1 ? NG - 1 : t);
    idx = t;
    w = (v - borders[t]) * inv_len[t];
}

__device__ __forceinline__ __half2 u2h(unsigned u) {
    union { unsigned u; __half2 h; } v; v.u = u; return v.h;
}
__device__ __forceinline__ unsigned h2u(__half2 h) {
    union { unsigned u; __half2 h; } v; v.h = h; return v.u;
}

// 32768 threads: gid<16384 -> x table, else z table. Also zeroes out[] (32768).
__global__ void precompute_kernel(const float* __restrict__ x,
                                  const float* __restrict__ z,
                                  const float* __restrict__ borders,
                                  const float* __restrict__ inv_len,
                                  float2* __restrict__ xc,   // [32*512]
                                  uint2* __restrict__ zc,    // [32*512]
                                  float* __restrict__ out) {
    const int gid = blockIdx.x * blockDim.x + threadIdx.x;
    out[gid] = 0.f;
    int idx; float w;
    if (gid < IN_X * BATCH) {
        grid_coord(x[gid], borders, inv_len, idx, w);
        xc[gid] = make_float2(w, __int_as_float(idx * XSTR));
    } else {
        const int g = gid - IN_X * BATCH;
        grid_coord(z[g], borders, inv_len, idx, w);
        zc[g] = make_uint2(h2u(__float2half2_rn(w)),
                           (unsigned)(idx * LDS_STR));
    }
}

__global__ __launch_bounds__(512, 8)
void bf2d_kernel(const float2* __restrict__ xc,
                 const uint2* __restrict__ zc,
                 const float* __restrict__ P,
                 float* __restrict__ out) {
    // lds[e] = packed f16 (P[cell,o0,i,j], P[cell,o1,i,j]), e = cell*33 + j
    __shared__ unsigned lds[CELLS * LDS_STR];   // 9537 dwords = 38148 B

    const int tid = threadIdx.x;                // 512 threads = batch element
    const int o0  = (blockIdx.x & 31) * 2;      // o-pair
    const int i   = blockIdx.x >> 5;

    // ---- stage P[:, :, {o0,o0+1}, i, :] into LDS as packed f16 ----
    const float* Pbase = P + ((size_t)o0 * (IN_X * IN_Z) + (size_t)i * IN_Z);
    for (int k = tid; k < CELLS * IN_Z; k += 512) {
        const int c = k >> 5;                   // cell = gx*17 + gz
        const int j = k & 31;
        const size_t g = (size_t)c * (OUT_DIM * IN_X * IN_Z) + j;
        lds[c * LDS_STR + j] =
            h2u(__floats2half2_rn(Pbase[g], Pbase[g + IN_X * IN_Z]));
    }
    __syncthreads();

    // ---- per-thread: 1 batch element, 2 outputs, packed-f16 lerps ----
    const float2  xcv = xc[i * BATCH + tid];
    const __half2 wx2 = __float2half2_rn(xcv.x);
    const int    xoff = __float_as_int(xcv.y);

    const uint2* zp = zc + tid;
    float accx = 0.f, accy = 0.f;
    #pragma unroll 8
    for (int j = 0; j < IN_Z; ++j) {
        const uint2   zcv = zp[j * BATCH];          // L2-resident table
        const __half2 wz2 = u2h(zcv.x);
        const int    base = xoff + (int)zcv.y + j;
        const __half2 a0 = u2h(lds[base]);              // (gx  ,gz  ) o-pair
        const __half2 a1 = u2h(lds[base + LDS_STR]);    // (gx  ,gz+1) ds_read2
        const __half2 b0 = u2h(lds[base + XSTR]);       // (gx+1,gz  )
        const __half2 b1 = u2h(lds[base + XSTR + LDS_STR]);
        const __half2 lo = __hfma2(wz2, __hsub2(a1, a0), a0);
        const __half2 hi = __hfma2(wz2, __hsub2(b1, b0), b0);
        const __half2 r  = __hfma2(wx2, __hsub2(hi, lo), lo);
        const float2  f  = __half22float2(r);
        accx += f.x;
        accy += f.y;
    }

    atomicAdd(&out[o0 * BATCH + tid],       accx);
    atomicAdd(&out[(o0 + 1) * BATCH + tid], accy);
}

extern "C" void kernel_launch(void* const* d_in, const int* in_sizes, int n_in,
                              void* d_out, int out_size, void* d_ws, size_t ws_size,
                              hipStream_t stream) {
    const float* x       = (const float*)d_in[0];   // (32, 512)
    const float* z       = (const float*)d_in[1];   // (32, 512)
    const float* P       = (const float*)d_in[2];   // (17,17,64,32,32)
    const float* borders = (const float*)d_in[3];   // (17,)
    const float* inv_len = (const float*)d_in[4];   // (16,)
    float* out = (float*)d_out;                     // (64, 512) = 32768

    float2* xc = (float2*)d_ws;                     // 16384 float2
    uint2*  zc = (uint2*)(xc + IN_X * BATCH);       // 16384 uint2

    precompute_kernel<<<dim3(128), dim3(256), 0, stream>>>(
        x, z, borders, inv_len, xc, zc, out);

    bf2d_kernel<<<dim3((OUT_DIM / 2) * IN_X), dim3(512), 0, stream>>>(
        xc, zc, P, out);
}